// Round 9
// baseline (170.624 us; speedup 1.0000x reference)
//
#include <hip/hip_runtime.h>
#include <stdint.h>

#define N_VOX   (1 << 19)
#define CIN     64
#define COUT    128
#define BIN_SHIFT 3
#define BINS    (1 << 20)          // (4*8*512*512) >> 3, lambda = 0.5/bin
#define OFF_BITS 4                 // intra-bin arrival offset
#define BPB     256                // bins per k_mega block (~128 positions)
#define NTILES  1024               // scan tiles (1024 bins each)
#define PCAP    512                // max positions per mega block (Poisson(128))
#define EPSV    1e-5f

typedef float f32x4 __attribute__((ext_vector_type(4)));

static __device__ __forceinline__ void nt_store4(float* p, f32x4 v) {
    __builtin_nontemporal_store(v, (f32x4*)p);
}

// d_out: out_f [N,128] f32 | new_idx [N,4] f32.
// valid row <=> (lin & 0x201)==0. lin = b<<21 | t<<18 | y<<9 | x.
// ws ints: hist[BINS] | ticket(1)+pad(3) | tiles[2*NTILES] | cursor[BINS]
//          | packed[N] | perm[N]

#define CLR_INTS (BINS + 4 + 2 * NTILES)

__global__ void k_clear(int* __restrict__ p) {
    int t = blockIdx.x * 256 + threadIdx.x;
    if (t * 4 < CLR_INTS) *(int4*)&p[t * 4] = make_int4(0, 0, 0, 0);
}

__global__ void k_hist(const int* __restrict__ idx, unsigned* __restrict__ packed,
                       int* __restrict__ hist) {
    int j = blockIdx.x * 256 + threadIdx.x;
    int4 v = *(const int4*)&idx[j * 4];
    int lin = ((v.x * 8 + v.y) * 512 + v.z) * 512 + v.w;
    int off = atomicAdd(&hist[lin >> BIN_SHIFT], 1);
    packed[j] = ((unsigned)lin << OFF_BITS) | (unsigned)off;
}

// single-kernel exclusive scan, decoupled lookback, ticket-ordered tiles.
// tiles[t] = (status << 40) | value; status 1=aggregate, 2=inclusive.
__global__ __launch_bounds__(256) void k_scan(
    const int* __restrict__ hist, int* __restrict__ cursor,
    unsigned long long* __restrict__ tiles, int* __restrict__ ticket) {
    __shared__ int stile;
    __shared__ int wsums[4];
    __shared__ int sprefix;
    int tid = threadIdx.x;
    if (tid == 0) stile = atomicAdd(ticket, 1);
    __syncthreads();
    int tile = stile;
    int base = tile * 1024 + tid * 4;
    int4 v = *(const int4*)&hist[base];
    int t3 = v.x + v.y + v.z + v.w;
    int lane = tid & 63, w = tid >> 6;
    int incl = t3;
    #pragma unroll
    for (int off = 1; off < 64; off <<= 1) {
        int u = __shfl_up(incl, off);
        if (lane >= off) incl += u;
    }
    if (lane == 63) wsums[w] = incl;
    __syncthreads();
    int woff = (w > 0 ? wsums[0] : 0) + (w > 1 ? wsums[1] : 0) + (w > 2 ? wsums[2] : 0);
    int total = wsums[0] + wsums[1] + wsums[2] + wsums[3];
    int texcl = woff + incl - t3;          // exclusive prefix of this thread in tile
    if (tid == 0) {
        unsigned long long st = (tile == 0) ? 2ull : 1ull;
        unsigned long long val = (tile == 0) ? (unsigned long long)(unsigned)total
                                             : (unsigned long long)(unsigned)total;
        atomicExch(&tiles[tile], (st << 40) | val);
        int pfx = 0;
        if (tile > 0) {
            int p = tile - 1;
            while (true) {
                unsigned long long d = atomicAdd(&tiles[p], 0ull);
                unsigned long long st2 = d >> 40;
                if (st2 == 0) { __builtin_amdgcn_s_sleep(2); continue; }
                pfx += (int)(unsigned)(d & 0xFFFFFFFFull);
                if (st2 == 2ull) break;
                p--;
            }
            atomicExch(&tiles[tile],
                       (2ull << 40) | (unsigned long long)(unsigned)(pfx + total));
        }
        sprefix = pfx;
    }
    __syncthreads();
    int prefix = sprefix + texcl;
    int4 e;
    e.x = prefix;
    e.y = prefix + v.x;
    e.z = prefix + v.x + v.y;
    e.w = prefix + v.x + v.y + v.z;
    *(int4*)&cursor[base] = e;             // cursor = bin start (exclusive scan)
}

__global__ void k_scatter(const unsigned* __restrict__ packed, const int* __restrict__ cursor,
                          int* __restrict__ perm) {
    int j = blockIdx.x * 256 + threadIdx.x;
    unsigned p = packed[j];
    int pos = cursor[p >> (OFF_BITS + BIN_SHIFT)] + (int)(p & ((1u << OFF_BITS) - 1u));
    perm[pos] = j;
}

// ---------- fused fixup + finalize + GEMM + LN ----------
__global__ __launch_bounds__(256) void k_mega(
    const float* __restrict__ feats, const float* __restrict__ weight,
    const float* __restrict__ gamma, const float* __restrict__ beta,
    const int* __restrict__ hist, const int* __restrict__ cursor,
    const unsigned* __restrict__ packed, int* __restrict__ perm,
    float* __restrict__ out) {
    __shared__ float featb[4][8][CIN];         // 8 KB (wave-private slices)
    __shared__ unsigned slin[PCAP];            // 2 KB  lin per local position
    __shared__ int sperm[PCAP];                // 2 KB  orig row per local position
    __shared__ unsigned short vpos[PCAP];      // 1 KB  local offsets of valid rows
    __shared__ unsigned ibit[PCAP / 32];       // invalid bitmap
    __shared__ int wsum[4];

    int tid = threadIdx.x;
    int w = tid >> 6, lane = tid & 63;
    int B0 = blockIdx.x * BPB;
    int p0 = cursor[B0];
    int p1 = (B0 + BPB < BINS) ? cursor[B0 + BPB] : N_VOX;
    int npos = p1 - p0;                        // ~Poisson(128), < PCAP

    if (tid < PCAP / 32) ibit[tid] = 0;

    // Phase A: per-bin stable fixup (key = lin<<19 | j); cache lin/perm in LDS
    int b = B0 + tid;
    int c = hist[b];
    int s = cursor[b];
    if (c >= 2) {
        for (int i = 1; i < c; i++) {
            int pj = perm[s + i];
            unsigned long long kj =
                ((unsigned long long)(packed[pj] >> OFF_BITS) << 19) | (unsigned)pj;
            int m = i - 1;
            while (m >= 0) {
                int pm = perm[s + m];
                unsigned long long km =
                    ((unsigned long long)(packed[pm] >> OFF_BITS) << 19) | (unsigned)pm;
                if (km <= kj) break;
                perm[s + m + 1] = pm;
                m--;
            }
            perm[s + m + 1] = pj;
        }
    }
    int myv = 0;
    for (int i = 0; i < c; i++) {
        int lp = s - p0 + i;
        int j = perm[s + i];
        unsigned lin = packed[j] >> OFF_BITS;
        slin[lp] = lin;
        sperm[lp] = j;
        myv += ((lin & 0x201u) == 0u) ? 1 : 0;
    }
    // block-exclusive scan of myv (wave shuffle + 1 barrier)
    int incl = myv;
    #pragma unroll
    for (int off = 1; off < 64; off <<= 1) {
        int u = __shfl_up(incl, off);
        if (lane >= off) incl += u;
    }
    if (lane == 63) wsum[w] = incl;
    __syncthreads();
    int s0 = wsum[0], s1 = wsum[1], s2 = wsum[2], s3 = wsum[3];
    int nv = s0 + s1 + s2 + s3;
    int woff = (w > 0 ? s0 : 0) + (w > 1 ? s1 : 0) + (w > 2 ? s2 : 0);
    int basev = woff + incl - myv;
    for (int i = 0; i < c; i++) {
        int lp = s - p0 + i;
        if ((slin[lp] & 0x201u) == 0u) vpos[basev++] = (unsigned short)lp;
        else atomicOr(&ibit[lp >> 5], 1u << (lp & 31));
    }
    __syncthreads();

    int half = lane >> 5, l32 = lane & 31;

    // Phase B: invalid rows -> new_idx = -1, zero feature rows (nt stores)
    {
        f32x4 mi = {-1.f, -1.f, -1.f, -1.f};
        for (int lp = tid; lp < npos; lp += 256) {
            if ((ibit[lp >> 5] >> (lp & 31)) & 1u)
                nt_store4(&out[(size_t)N_VOX * COUT + (size_t)(p0 + lp) * 4], mi);
        }
        f32x4 z = {0.f, 0.f, 0.f, 0.f};
        for (int lp = w * 2 + half; lp < npos; lp += 8) {
            if ((ibit[lp >> 5] >> (lp & 31)) & 1u)
                nt_store4(&out[(size_t)(p0 + lp) * COUT + l32 * 4], z);
        }
    }

    // Phase C: GEMM + LN, 2 rows per wave pass (halves), 4 ch/lane, f32x4 stores
    if (nv == 0) return;
    const f32x4* Wg4 = (const f32x4*)weight;   // [64][32] of float4
    f32x4 gv = *(const f32x4*)&gamma[l32 * 4];
    f32x4 bv = *(const f32x4*)&beta[l32 * 4];

    for (int m0 = 0; m0 < nv; m0 += 32) {
        int mb = m0 + w * 8;
        if (mb >= nv) continue;                 // no barriers below: safe
        #pragma unroll
        for (int i = 0; i < 8; i++) {
            int m = mb + i;
            int lp = vpos[(m < nv) ? m : 0];
            featb[w][i][lane] = feats[(size_t)sperm[lp] * CIN + lane];
        }

        f32x4 acc[4];
        #pragma unroll
        for (int i = 0; i < 4; i++) acc[i] = (f32x4){0.f, 0.f, 0.f, 0.f};

        #pragma unroll 4
        for (int k0 = 0; k0 < CIN; k0 += 4) {
            f32x4 wv0 = Wg4[(k0 + 0) * 32 + l32];
            f32x4 wv1 = Wg4[(k0 + 1) * 32 + l32];
            f32x4 wv2 = Wg4[(k0 + 2) * 32 + l32];
            f32x4 wv3 = Wg4[(k0 + 3) * 32 + l32];
            #pragma unroll
            for (int ii = 0; ii < 4; ii++) {
                // lanes 0-31: row 2*ii; lanes 32-63: row 2*ii+1 (LDS broadcast per half)
                float4 f = *(float4*)&featb[w][2 * ii + half][k0];
                acc[ii] += f.x * wv0;
                acc[ii] += f.y * wv1;
                acc[ii] += f.z * wv2;
                acc[ii] += f.w * wv3;
            }
        }

        #pragma unroll
        for (int ii = 0; ii < 4; ii++) {
            int m = mb + 2 * ii + half;
            f32x4 a = acc[ii];
            float sm = a.x + a.y + a.z + a.w;
            float sq = a.x * a.x + a.y * a.y + a.z * a.z + a.w * a.w;
            #pragma unroll
            for (int off = 16; off > 0; off >>= 1) {   // reduce within 32-lane half
                sm += __shfl_xor(sm, off);
                sq += __shfl_xor(sq, off);
            }
            float mean = sm * (1.0f / COUT);
            float var  = fmaxf(sq * (1.0f / COUT) - mean * mean, 0.0f);
            float rstd = rsqrtf(var + EPSV);
            if (m < nv) {
                int lp = vpos[m];
                int pos = p0 + lp;
                f32x4 o = (a - mean) * rstd * gv + bv;
                nt_store4(&out[(size_t)pos * COUT + l32 * 4], o);
                if (l32 == 0) {
                    unsigned lin = slin[lp];
                    f32x4 ni;
                    ni.x = (float)(lin >> 21);
                    ni.y = (float)((lin >> 18) & 7u);
                    ni.z = (float)(((lin >> 9) & 511u) >> 1);
                    ni.w = (float)((lin & 511u) >> 1);
                    nt_store4(&out[(size_t)N_VOX * COUT + (size_t)pos * 4], ni);
                }
            }
        }
    }
}

extern "C" void kernel_launch(void* const* d_in, const int* in_sizes, int n_in,
                              void* d_out, int out_size, void* d_ws, size_t ws_size,
                              hipStream_t stream) {
    const float* feats  = (const float*)d_in[0];
    const int*   idx    = (const int*)d_in[1];
    const float* weight = (const float*)d_in[2];
    const float* gamma  = (const float*)d_in[3];
    const float* beta   = (const float*)d_in[4];
    float* out = (float*)d_out;

    int* ws = (int*)d_ws;
    int*                hist   = ws;                         // BINS
    int*                ticket = ws + BINS;                  // 1 (+3 pad)
    unsigned long long* tiles  = (unsigned long long*)(ws + BINS + 4);  // NTILES
    int*                cursor = ws + BINS + 4 + 2 * NTILES; // BINS
    unsigned*           packed = (unsigned*)(cursor + BINS); // N
    int*                perm   = (int*)(packed + N_VOX);     // N

    k_clear<<<(CLR_INTS / 4 + 255) / 256, 256, 0, stream>>>(ws);
    k_hist<<<N_VOX / 256, 256, 0, stream>>>(idx, packed, hist);
    k_scan<<<NTILES, 256, 0, stream>>>(hist, cursor, tiles, ticket);
    k_scatter<<<N_VOX / 256, 256, 0, stream>>>(packed, cursor, perm);
    k_mega<<<BINS / BPB, 256, 0, stream>>>(feats, weight, gamma, beta,
                                           hist, cursor, packed, perm, out);
}